// Round 2
// baseline (14.708 us; speedup 1.0000x reference)
//
#include <hip/hip_runtime.h>

#define PROTON_F 1.00782503207f
#define WATER_F 18.0105646863f
#define HUBER_DELTA_F 0.2f

constexpr int B = 512;
constexpr int L = 64;
constexpr int V = 28;
constexpr int M = 1024;
constexpr int NT = 2 * (L - 1);   // 126 theoretical peaks
constexpr int THREADS = 256;
constexpr int MPT = M / THREADS;  // 4 observed peaks per thread

__global__ __launch_bounds__(THREADS)
void spectrum_loss_kernel(const float* __restrict__ probs,       // [B, L, V]
                          const float* __restrict__ obs_mass,    // [B, M]
                          const float* __restrict__ obs_int,     // [B, M]
                          const int* __restrict__ mask,          // [B, M] (bool -> int32)
                          const float* __restrict__ aa,          // [V]
                          float* __restrict__ per_b)             // [B]
{
    const int b = blockIdx.x;
    const int tid = threadIdx.x;

    __shared__ float s_probs[L * V];   // 1792 floats = 7 KiB
    __shared__ float s_prefix[L];
    __shared__ float s_T[NT];
    __shared__ float red_w[THREADS];
    __shared__ float red_i[THREADS];

    // Stage probs[b] into LDS (coalesced).
    const size_t pbase = (size_t)b * (L * V);
    for (int i = tid; i < L * V; i += THREADS)
        s_probs[i] = probs[pbase + i];
    __syncthreads();

    // r[l] = dot(probs[b,l,:], aa)  — threads 0..63
    if (tid < L) {
        float acc = 0.f;
        #pragma unroll
        for (int v = 0; v < V; ++v)
            acc += s_probs[tid * V + v] * aa[v];
        s_prefix[tid] = acc;
    }
    __syncthreads();

    // Sequential cumsum (64 adds, negligible; matches jnp.cumsum in f32).
    if (tid == 0) {
        float acc = 0.f;
        for (int l = 0; l < L; ++l) { acc += s_prefix[l]; s_prefix[l] = acc; }
    }
    __syncthreads();

    // Theoretical peaks: b_ions then y_ions.
    if (tid < NT) {
        const float total = s_prefix[L - 1];
        float tv;
        if (tid < L - 1) tv = s_prefix[tid] + PROTON_F;
        else             tv = total - s_prefix[tid - (L - 1)] + WATER_F + PROTON_F;
        s_T[tid] = tv;
    }
    __syncthreads();

    // Each thread handles MPT observed peaks; inner loop over 126 theoretical
    // peaks via LDS broadcast (uniform address -> conflict-free).
    float om[MPT], oi[MPT], mk[MPT], mind[MPT];
    const size_t obase = (size_t)b * M;
    #pragma unroll
    for (int k = 0; k < MPT; ++k) {
        const int m = tid + k * THREADS;
        om[k]   = obs_mass[obase + m];
        oi[k]   = obs_int[obase + m];
        mk[k]   = mask[obase + m] ? 1.f : 0.f;
        mind[k] = 1e30f;
    }

    #pragma unroll 2
    for (int t = 0; t < NT; ++t) {
        const float tv = s_T[t];
        #pragma unroll
        for (int k = 0; k < MPT; ++k)
            mind[k] = fminf(mind[k], fabsf(tv - om[k]));
    }

    float wsum = 0.f, isum = 0.f;
    #pragma unroll
    for (int k = 0; k < MPT; ++k) {
        const float d = mind[k];
        const float h = (d <= HUBER_DELTA_F)
                        ? 0.5f * d * d
                        : HUBER_DELTA_F * (d - 0.5f * HUBER_DELTA_F);
        wsum += h * oi[k] * mk[k];
        isum += oi[k];
    }

    // Deterministic block tree-reduction of both sums.
    red_w[tid] = wsum;
    red_i[tid] = isum;
    __syncthreads();
    for (int s = THREADS / 2; s > 0; s >>= 1) {
        if (tid < s) {
            red_w[tid] += red_w[tid + s];
            red_i[tid] += red_i[tid + s];
        }
        __syncthreads();
    }

    if (tid == 0)
        per_b[b] = red_w[0] / fmaxf(red_i[0], 1e-8f);
}

__global__ __launch_bounds__(B)
void final_reduce_kernel(const float* __restrict__ per_b, float* __restrict__ out)
{
    __shared__ float red[B];
    const int tid = threadIdx.x;
    red[tid] = per_b[tid];
    __syncthreads();
    for (int s = B / 2; s > 0; s >>= 1) {
        if (tid < s) red[tid] += red[tid + s];
        __syncthreads();
    }
    if (tid == 0) out[0] = red[0] * (1.0f / (float)B);
}

extern "C" void kernel_launch(void* const* d_in, const int* in_sizes, int n_in,
                              void* d_out, int out_size, void* d_ws, size_t ws_size,
                              hipStream_t stream)
{
    const float* probs = (const float*)d_in[0];          // (B, L, V)
    const float* omass = (const float*)d_in[1];          // (B, M)
    const float* oint  = (const float*)d_in[2];          // (B, M)
    const int*   pmask = (const int*)d_in[3];            // (B, M) bool -> int32
    const float* aa    = (const float*)d_in[4];          // (V,)
    float* out  = (float*)d_out;
    float* perb = (float*)d_ws;  // B floats of scratch

    spectrum_loss_kernel<<<B, THREADS, 0, stream>>>(probs, omass, oint, pmask, aa, perb);
    final_reduce_kernel<<<1, B, 0, stream>>>(perb, out);
}